// Round 1
// baseline (158.034 us; speedup 1.0000x reference)
//
#include <hip/hip_runtime.h>

// Batched Kalman filter update: B=262144 independent 8-state / 4-obs updates.
// One thread per batch; everything in registers; memory-bound design.
constexpr int B_N = 262144;
constexpr int DX  = 8;
constexpr int DZ  = 4;

__global__ __launch_bounds__(256) void kalman_update(
    const float* __restrict__ x_in,   // [B, 8, 1]
    const float* __restrict__ z_in,   // [B, 4, 1]
    const float* __restrict__ P_in,   // [B, 8, 8]
    const float* __restrict__ H_in,   // [4, 8]   (uniform)
    const float* __restrict__ R_in,   // [4, 4]   (uniform)
    float* __restrict__ out)          // [B, 9, 8] = cat(x_new^T, P_new)
{
    const int b = blockIdx.x * 256 + threadIdx.x;
    if (b >= B_N) return;

    // ---- uniform small matrices (wave-uniform address -> expect SGPRs) ----
    float H[DZ][DX];
#pragma unroll
    for (int i = 0; i < DZ * DX; ++i) H[i / DX][i % DX] = H_in[i];
    float R[DZ][DZ];
#pragma unroll
    for (int i = 0; i < DZ * DZ; ++i) R[i / DZ][i % DZ] = R_in[i];

    // ---- per-batch vector loads ----
    float x[DX];
    {
        const float4* p = reinterpret_cast<const float4*>(x_in + (size_t)b * DX);
        float4 a = p[0], c = p[1];
        x[0] = a.x; x[1] = a.y; x[2] = a.z; x[3] = a.w;
        x[4] = c.x; x[5] = c.y; x[6] = c.z; x[7] = c.w;
    }
    float y[DZ];
    {
        const float4* p = reinterpret_cast<const float4*>(z_in + (size_t)b * DZ);
        float4 a = p[0];
        y[0] = a.x; y[1] = a.y; y[2] = a.z; y[3] = a.w;
    }
    float P[DX][DX];
    {
        const float4* p = reinterpret_cast<const float4*>(P_in + (size_t)b * DX * DX);
#pragma unroll
        for (int i = 0; i < 16; ++i) {
            float4 a = p[i];
            const int r = i >> 1, c = (i & 1) * 4;
            P[r][c + 0] = a.x; P[r][c + 1] = a.y; P[r][c + 2] = a.z; P[r][c + 3] = a.w;
        }
    }

    // ---- y = z - H x  (innovation) ----
#pragma unroll
    for (int zi = 0; zi < DZ; ++zi) {
        float acc = 0.f;
#pragma unroll
        for (int k = 0; k < DX; ++k) acc += H[zi][k] * x[k];
        y[zi] -= acc;
    }

    // ---- PHT = P H^T  [8][4] ----
    float PHT[DX][DZ];
#pragma unroll
    for (int i = 0; i < DX; ++i)
#pragma unroll
        for (int j = 0; j < DZ; ++j) {
            float acc = 0.f;
#pragma unroll
            for (int k = 0; k < DX; ++k) acc += P[i][k] * H[j][k];
            PHT[i][j] = acc;
        }

    // ---- S = H PHT + R  [4][4] ----
    float S[DZ][DZ];
#pragma unroll
    for (int a = 0; a < DZ; ++a)
#pragma unroll
        for (int c = 0; c < DZ; ++c) {
            float acc = R[a][c];
#pragma unroll
            for (int k = 0; k < DX; ++k) acc += H[a][k] * PHT[k][c];
            S[a][c] = acc;
        }

    // ---- SI = inv(S) via adjugate (S is SPD, well conditioned: R = I) ----
    float SI[DZ][DZ];
    {
        const float A2323 = S[2][2]*S[3][3] - S[2][3]*S[3][2];
        const float A1323 = S[2][1]*S[3][3] - S[2][3]*S[3][1];
        const float A1223 = S[2][1]*S[3][2] - S[2][2]*S[3][1];
        const float A0323 = S[2][0]*S[3][3] - S[2][3]*S[3][0];
        const float A0223 = S[2][0]*S[3][2] - S[2][2]*S[3][0];
        const float A0123 = S[2][0]*S[3][1] - S[2][1]*S[3][0];
        const float A2313 = S[1][2]*S[3][3] - S[1][3]*S[3][2];
        const float A1313 = S[1][1]*S[3][3] - S[1][3]*S[3][1];
        const float A1213 = S[1][1]*S[3][2] - S[1][2]*S[3][1];
        const float A2312 = S[1][2]*S[2][3] - S[1][3]*S[2][2];
        const float A1312 = S[1][1]*S[2][3] - S[1][3]*S[2][1];
        const float A1212 = S[1][1]*S[2][2] - S[1][2]*S[2][1];
        const float A0313 = S[1][0]*S[3][3] - S[1][3]*S[3][0];
        const float A0213 = S[1][0]*S[3][2] - S[1][2]*S[3][0];
        const float A0312 = S[1][0]*S[2][3] - S[1][3]*S[2][0];
        const float A0212 = S[1][0]*S[2][2] - S[1][2]*S[2][0];
        const float A0113 = S[1][0]*S[3][1] - S[1][1]*S[3][0];
        const float A0112 = S[1][0]*S[2][1] - S[1][1]*S[2][0];

        float det = S[0][0] * (S[1][1]*A2323 - S[1][2]*A1323 + S[1][3]*A1223)
                  - S[0][1] * (S[1][0]*A2323 - S[1][2]*A0323 + S[1][3]*A0223)
                  + S[0][2] * (S[1][0]*A1323 - S[1][1]*A0323 + S[1][3]*A0123)
                  - S[0][3] * (S[1][0]*A1223 - S[1][1]*A0223 + S[1][2]*A0123);
        const float id = 1.0f / det;

        SI[0][0] = id *  (S[1][1]*A2323 - S[1][2]*A1323 + S[1][3]*A1223);
        SI[0][1] = id * -(S[0][1]*A2323 - S[0][2]*A1323 + S[0][3]*A1223);
        SI[0][2] = id *  (S[0][1]*A2313 - S[0][2]*A1313 + S[0][3]*A1213);
        SI[0][3] = id * -(S[0][1]*A2312 - S[0][2]*A1312 + S[0][3]*A1212);
        SI[1][0] = id * -(S[1][0]*A2323 - S[1][2]*A0323 + S[1][3]*A0223);
        SI[1][1] = id *  (S[0][0]*A2323 - S[0][2]*A0323 + S[0][3]*A0223);
        SI[1][2] = id * -(S[0][0]*A2313 - S[0][2]*A0313 + S[0][3]*A0213);
        SI[1][3] = id *  (S[0][0]*A2312 - S[0][2]*A0312 + S[0][3]*A0212);
        SI[2][0] = id *  (S[1][0]*A1323 - S[1][1]*A0323 + S[1][3]*A0123);
        SI[2][1] = id * -(S[0][0]*A1323 - S[0][1]*A0323 + S[0][3]*A0123);
        SI[2][2] = id *  (S[0][0]*A1313 - S[0][1]*A0313 + S[0][3]*A0113);
        SI[2][3] = id * -(S[0][0]*A1312 - S[0][1]*A0312 + S[0][3]*A0112);
        SI[3][0] = id * -(S[1][0]*A1223 - S[1][1]*A0223 + S[1][2]*A0123);
        SI[3][1] = id *  (S[0][0]*A1223 - S[0][1]*A0223 + S[0][2]*A0123);
        SI[3][2] = id * -(S[0][0]*A1213 - S[0][1]*A0213 + S[0][2]*A0113);
        SI[3][3] = id *  (S[0][0]*A1212 - S[0][1]*A0212 + S[0][2]*A0112);
    }

    // ---- K = PHT * SI  [8][4] ----
    float K[DX][DZ];
#pragma unroll
    for (int i = 0; i < DX; ++i)
#pragma unroll
        for (int j = 0; j < DZ; ++j) {
            float acc = 0.f;
#pragma unroll
            for (int w = 0; w < DZ; ++w) acc += PHT[i][w] * SI[w][j];
            K[i][j] = acc;
        }

    // ---- x_new = x + K y ; store row 0 of output ----
    {
        float xn[DX];
#pragma unroll
        for (int i = 0; i < DX; ++i) {
            float acc = x[i];
#pragma unroll
            for (int zi = 0; zi < DZ; ++zi) acc += K[i][zi] * y[zi];
            xn[i] = acc;
        }
        float4* o = reinterpret_cast<float4*>(out + (size_t)b * 72);
        o[0] = make_float4(xn[0], xn[1], xn[2], xn[3]);
        o[1] = make_float4(xn[4], xn[5], xn[6], xn[7]);
    }

    // ---- B = (I - K H) P = P - K (H P) ; H P = PHT^T since P symmetric ----
    // In-place on P.
#pragma unroll
    for (int i = 0; i < DX; ++i)
#pragma unroll
        for (int j = 0; j < DX; ++j) {
            float acc = P[i][j];
#pragma unroll
            for (int zi = 0; zi < DZ; ++zi) acc -= K[i][zi] * PHT[j][zi];
            P[i][j] = acc;
        }

    // ---- E = K R - B H^T  [8][4] ----
    float E[DX][DZ];
#pragma unroll
    for (int i = 0; i < DX; ++i)
#pragma unroll
        for (int zi = 0; zi < DZ; ++zi) {
            float acc = 0.f;
#pragma unroll
            for (int w = 0; w < DZ; ++w) acc += K[i][w] * R[w][zi];
#pragma unroll
            for (int k = 0; k < DX; ++k) acc -= P[i][k] * H[zi][k];
            E[i][zi] = acc;
        }

    // ---- P_new = B + E K^T  (in-place on P) ; store rows 1..8 ----
#pragma unroll
    for (int i = 0; i < DX; ++i) {
#pragma unroll
        for (int j = 0; j < DX; ++j) {
            float acc = P[i][j];
#pragma unroll
            for (int zi = 0; zi < DZ; ++zi) acc += E[i][zi] * K[j][zi];
            P[i][j] = acc;
        }
        float4* o = reinterpret_cast<float4*>(out + (size_t)b * 72 + 8 + (size_t)i * 8);
        o[0] = make_float4(P[i][0], P[i][1], P[i][2], P[i][3]);
        o[1] = make_float4(P[i][4], P[i][5], P[i][6], P[i][7]);
    }
}

extern "C" void kernel_launch(void* const* d_in, const int* in_sizes, int n_in,
                              void* d_out, int out_size, void* d_ws, size_t ws_size,
                              hipStream_t stream) {
    const float* x = (const float*)d_in[0];
    const float* z = (const float*)d_in[1];
    const float* P = (const float*)d_in[2];
    const float* H = (const float*)d_in[3];
    const float* R = (const float*)d_in[4];
    float* out = (float*)d_out;

    dim3 grid(B_N / 256), block(256);
    hipLaunchKernelGGL(kalman_update, grid, block, 0, stream, x, z, P, H, R, out);
}

// Round 2
// 145.790 us; speedup vs baseline: 1.0840x; 1.0840x over previous
//
#include <hip/hip_runtime.h>

// Batched Kalman filter update: B=262144 independent 8-state / 4-obs updates.
// One thread per batch. All large traffic (P in, out) staged through wave-local
// LDS slices so every global access is fully coalesced; XOR swizzles keep LDS
// at the b128 bank floor. No __syncthreads needed (wave-private slices).
constexpr int B_N = 262144;
constexpr int DX  = 8;
constexpr int DZ  = 4;

// float4-index swizzles (involutions; applied identically on write & read)
__device__ __forceinline__ int swzP(int i) { return i ^ ((i >> 4) & 7); } // domain [0,1024)
__device__ __forceinline__ int swzX(int i) { return i ^ ((i >> 3) & 1); } // domain [0,128)
__device__ __forceinline__ int swzO(int i) { return i ^ ((i >> 3) & 1); } // domain [0,1152)

__global__ __launch_bounds__(256) void kalman_update(
    const float* __restrict__ x_in,   // [B, 8, 1]
    const float* __restrict__ z_in,   // [B, 4, 1]
    const float* __restrict__ P_in,   // [B, 8, 8]
    const float* __restrict__ H_in,   // [4, 8]   (uniform)
    const float* __restrict__ R_in,   // [4, 4]   (uniform)
    float* __restrict__ out)          // [B, 9, 8] = cat(x_new^T, P_new)
{
    // Per-wave LDS slice: 1152 float4 = 18 KiB (P stage: [0,1024), x stage:
    // [1024,1152); later reused for out stage: [0,1152)). 4 waves/block.
    __shared__ float4 lds[4 * 1152];

    const int wave = threadIdx.x >> 6;
    const int lane = threadIdx.x & 63;
    float4* const slice = lds + wave * 1152;

    const int wbatch = blockIdx.x * 256 + wave * 64;  // wave's first batch
    const int b      = wbatch + lane;                 // this thread's batch

    // ---- stage P: 64 batches x 16 float4, fully coalesced global reads ----
    {
        const float4* Pg = reinterpret_cast<const float4*>(P_in) + (size_t)wbatch * 16;
#pragma unroll
        for (int k = 0; k < 16; ++k) {
            const int d = 64 * k + lane;
            slice[swzP(d)] = Pg[d];
        }
        const float4* xg = reinterpret_cast<const float4*>(x_in) + (size_t)wbatch * 2;
#pragma unroll
        for (int k = 0; k < 2; ++k) {
            const int d = 64 * k + lane;
            slice[1024 + swzX(d)] = xg[d];
        }
    }

    // ---- z: 1 float4/batch, already coalesced ----
    float y[DZ];
    {
        const float4 a = reinterpret_cast<const float4*>(z_in)[b];
        y[0] = a.x; y[1] = a.y; y[2] = a.z; y[3] = a.w;
    }

    // ---- uniform small matrices ----
    float H[DZ][DX];
#pragma unroll
    for (int i = 0; i < DZ * DX; ++i) H[i / DX][i % DX] = H_in[i];
    float R[DZ][DZ];
#pragma unroll
    for (int i = 0; i < DZ * DZ; ++i) R[i / DZ][i % DZ] = R_in[i];

    // ---- read this thread's x, P from LDS (b128, bank-floor) ----
    float x[DX];
    {
        const float4 a = slice[1024 + swzX(2 * lane + 0)];
        const float4 c = slice[1024 + swzX(2 * lane + 1)];
        x[0] = a.x; x[1] = a.y; x[2] = a.z; x[3] = a.w;
        x[4] = c.x; x[5] = c.y; x[6] = c.z; x[7] = c.w;
    }
    float P[DX][DX];
#pragma unroll
    for (int c16 = 0; c16 < 16; ++c16) {
        const float4 v = slice[swzP(16 * lane + c16)];
        const int r = c16 >> 1, c = (c16 & 1) * 4;
        P[r][c + 0] = v.x; P[r][c + 1] = v.y; P[r][c + 2] = v.z; P[r][c + 3] = v.w;
    }

    // ---- y = z - H x ----
#pragma unroll
    for (int zi = 0; zi < DZ; ++zi) {
        float acc = 0.f;
#pragma unroll
        for (int k = 0; k < DX; ++k) acc += H[zi][k] * x[k];
        y[zi] -= acc;
    }

    // ---- PHT = P H^T [8][4] ----
    float PHT[DX][DZ];
#pragma unroll
    for (int i = 0; i < DX; ++i)
#pragma unroll
        for (int j = 0; j < DZ; ++j) {
            float acc = 0.f;
#pragma unroll
            for (int k = 0; k < DX; ++k) acc += P[i][k] * H[j][k];
            PHT[i][j] = acc;
        }

    // ---- S = H PHT + R [4][4] ----
    float S[DZ][DZ];
#pragma unroll
    for (int a = 0; a < DZ; ++a)
#pragma unroll
        for (int c = 0; c < DZ; ++c) {
            float acc = R[a][c];
#pragma unroll
            for (int k = 0; k < DX; ++k) acc += H[a][k] * PHT[k][c];
            S[a][c] = acc;
        }

    // ---- SI = inv(S) via adjugate (S SPD, well conditioned: R = I) ----
    float SI[DZ][DZ];
    {
        const float A2323 = S[2][2]*S[3][3] - S[2][3]*S[3][2];
        const float A1323 = S[2][1]*S[3][3] - S[2][3]*S[3][1];
        const float A1223 = S[2][1]*S[3][2] - S[2][2]*S[3][1];
        const float A0323 = S[2][0]*S[3][3] - S[2][3]*S[3][0];
        const float A0223 = S[2][0]*S[3][2] - S[2][2]*S[3][0];
        const float A0123 = S[2][0]*S[3][1] - S[2][1]*S[3][0];
        const float A2313 = S[1][2]*S[3][3] - S[1][3]*S[3][2];
        const float A1313 = S[1][1]*S[3][3] - S[1][3]*S[3][1];
        const float A1213 = S[1][1]*S[3][2] - S[1][2]*S[3][1];
        const float A2312 = S[1][2]*S[2][3] - S[1][3]*S[2][2];
        const float A1312 = S[1][1]*S[2][3] - S[1][3]*S[2][1];
        const float A1212 = S[1][1]*S[2][2] - S[1][2]*S[2][1];
        const float A0313 = S[1][0]*S[3][3] - S[1][3]*S[3][0];
        const float A0213 = S[1][0]*S[3][2] - S[1][2]*S[3][0];
        const float A0312 = S[1][0]*S[2][3] - S[1][3]*S[2][0];
        const float A0212 = S[1][0]*S[2][2] - S[1][2]*S[2][0];
        const float A0113 = S[1][0]*S[3][1] - S[1][1]*S[3][0];
        const float A0112 = S[1][0]*S[2][1] - S[1][1]*S[2][0];

        float det = S[0][0] * (S[1][1]*A2323 - S[1][2]*A1323 + S[1][3]*A1223)
                  - S[0][1] * (S[1][0]*A2323 - S[1][2]*A0323 + S[1][3]*A0223)
                  + S[0][2] * (S[1][0]*A1323 - S[1][1]*A0323 + S[1][3]*A0123)
                  - S[0][3] * (S[1][0]*A1223 - S[1][1]*A0223 + S[1][2]*A0123);
        const float id = 1.0f / det;

        SI[0][0] = id *  (S[1][1]*A2323 - S[1][2]*A1323 + S[1][3]*A1223);
        SI[0][1] = id * -(S[0][1]*A2323 - S[0][2]*A1323 + S[0][3]*A1223);
        SI[0][2] = id *  (S[0][1]*A2313 - S[0][2]*A1313 + S[0][3]*A1213);
        SI[0][3] = id * -(S[0][1]*A2312 - S[0][2]*A1312 + S[0][3]*A1212);
        SI[1][0] = id * -(S[1][0]*A2323 - S[1][2]*A0323 + S[1][3]*A0223);
        SI[1][1] = id *  (S[0][0]*A2323 - S[0][2]*A0323 + S[0][3]*A0223);
        SI[1][2] = id * -(S[0][0]*A2313 - S[0][2]*A0313 + S[0][3]*A0213);
        SI[1][3] = id *  (S[0][0]*A2312 - S[0][2]*A0312 + S[0][3]*A0212);
        SI[2][0] = id *  (S[1][0]*A1323 - S[1][1]*A0323 + S[1][3]*A0123);
        SI[2][1] = id * -(S[0][0]*A1323 - S[0][1]*A0323 + S[0][3]*A0123);
        SI[2][2] = id *  (S[0][0]*A1313 - S[0][1]*A0313 + S[0][3]*A0113);
        SI[2][3] = id * -(S[0][0]*A1312 - S[0][1]*A0312 + S[0][3]*A0112);
        SI[3][0] = id * -(S[1][0]*A1223 - S[1][1]*A0223 + S[1][2]*A0123);
        SI[3][1] = id *  (S[0][0]*A1223 - S[0][1]*A0223 + S[0][2]*A0123);
        SI[3][2] = id * -(S[0][0]*A1213 - S[0][1]*A0213 + S[0][2]*A0113);
        SI[3][3] = id *  (S[0][0]*A1212 - S[0][1]*A0212 + S[0][2]*A0112);
    }

    // ---- K = PHT * SI [8][4] ----
    float K[DX][DZ];
#pragma unroll
    for (int i = 0; i < DX; ++i)
#pragma unroll
        for (int j = 0; j < DZ; ++j) {
            float acc = 0.f;
#pragma unroll
            for (int w = 0; w < DZ; ++w) acc += PHT[i][w] * SI[w][j];
            K[i][j] = acc;
        }

    // ---- x_new = x + K y ; stage out row 0 (f4 slots 0,1 of this batch) ----
    {
        float xn[DX];
#pragma unroll
        for (int i = 0; i < DX; ++i) {
            float acc = x[i];
#pragma unroll
            for (int zi = 0; zi < DZ; ++zi) acc += K[i][zi] * y[zi];
            xn[i] = acc;
        }
        slice[swzO(18 * lane + 0)] = make_float4(xn[0], xn[1], xn[2], xn[3]);
        slice[swzO(18 * lane + 1)] = make_float4(xn[4], xn[5], xn[6], xn[7]);
    }

    // ---- B = (I - K H) P = P - K (H P); H P = PHT^T since P symmetric ----
#pragma unroll
    for (int i = 0; i < DX; ++i)
#pragma unroll
        for (int j = 0; j < DX; ++j) {
            float acc = P[i][j];
#pragma unroll
            for (int zi = 0; zi < DZ; ++zi) acc -= K[i][zi] * PHT[j][zi];
            P[i][j] = acc;
        }

    // ---- E = K R - B H^T [8][4] ----
    float E[DX][DZ];
#pragma unroll
    for (int i = 0; i < DX; ++i)
#pragma unroll
        for (int zi = 0; zi < DZ; ++zi) {
            float acc = 0.f;
#pragma unroll
            for (int w = 0; w < DZ; ++w) acc += K[i][w] * R[w][zi];
#pragma unroll
            for (int k = 0; k < DX; ++k) acc -= P[i][k] * H[zi][k];
            E[i][zi] = acc;
        }

    // ---- P_new = B + E K^T (in-place); stage rows 1..8 ----
#pragma unroll
    for (int i = 0; i < DX; ++i) {
#pragma unroll
        for (int j = 0; j < DX; ++j) {
            float acc = P[i][j];
#pragma unroll
            for (int zi = 0; zi < DZ; ++zi) acc += E[i][zi] * K[j][zi];
            P[i][j] = acc;
        }
        slice[swzO(18 * lane + 2 + 2 * i)]     = make_float4(P[i][0], P[i][1], P[i][2], P[i][3]);
        slice[swzO(18 * lane + 2 + 2 * i + 1)] = make_float4(P[i][4], P[i][5], P[i][6], P[i][7]);
    }

    // ---- flush out: 18 fully coalesced global stores per wave-batch-group ----
    {
        float4* Og = reinterpret_cast<float4*>(out) + (size_t)wbatch * 18;
#pragma unroll
        for (int k = 0; k < 18; ++k) {
            const int d = 64 * k + lane;
            Og[d] = slice[swzO(d)];
        }
    }
}

extern "C" void kernel_launch(void* const* d_in, const int* in_sizes, int n_in,
                              void* d_out, int out_size, void* d_ws, size_t ws_size,
                              hipStream_t stream) {
    const float* x = (const float*)d_in[0];
    const float* z = (const float*)d_in[1];
    const float* P = (const float*)d_in[2];
    const float* H = (const float*)d_in[3];
    const float* R = (const float*)d_in[4];
    float* out = (float*)d_out;

    dim3 grid(B_N / 256), block(256);
    hipLaunchKernelGGL(kalman_update, grid, block, 0, stream, x, z, P, H, R, out);
}